// Round 3
// baseline (424.086 us; speedup 1.0000x reference)
//
#include <hip/hip_runtime.h>
#include <hip/hip_cooperative_groups.h>
#include <hip/hip_bf16.h>
#include <math.h>

namespace cg = cooperative_groups;

// Problem constants
#define BB    128
#define TT    32
#define DD    1024
#define NADA  1024
#define NINT  1024
#define NRANK 8
#define LNEPS 1e-5f
#define TKCH  8                  // tmat k-chunks
#define XWN   (2 * DD * NRANK)   // 16384

using bf16x8 = __attribute__((ext_vector_type(8))) short;
using f32x4  = __attribute__((ext_vector_type(4))) float;

__device__ __forceinline__ short f2bf(float f) {
    __hip_bfloat16 h = __float2bfloat16(f);  // RNE
    return *reinterpret_cast<short*>(&h);
}

__device__ __forceinline__ float bf2f(short s) {
    unsigned u = ((unsigned)(unsigned short)s) << 16;
    return __uint_as_float(u);
}

__device__ __forceinline__ void async16(const void* g, void* l) {
    __builtin_amdgcn_global_load_lds(
        (const __attribute__((address_space(1))) void*)g,
        (__attribute__((address_space(3))) void*)l, 16, 0, 0);
}

// 64x64 transpose+cast tile (fp32 in -> bf16 out, out is [n][k] of in [k][n])
__device__ __forceinline__ void tcast_tile(
    const float* __restrict__ in, short* __restrict__ out, int K, int N,
    int bx, int by, bool addI, int tid, float (*t)[68])
{
    __syncthreads();   // protect LDS from previous job in same block
    const int n0 = bx * 64, k0 = by * 64;
    #pragma unroll
    for (int it = 0; it < 4; ++it) {
        const int idx = it * 256 + tid;
        const int r = idx >> 4, c4 = (idx & 15) * 4;
        float4 v = *(const float4*)(in + (size_t)(k0 + r) * N + n0 + c4);
        t[r][c4 + 0] = v.x; t[r][c4 + 1] = v.y;
        t[r][c4 + 2] = v.z; t[r][c4 + 3] = v.w;
    }
    __syncthreads();
    #pragma unroll
    for (int it = 0; it < 4; ++it) {
        const int idx = it * 256 + tid;
        const int rn = idx >> 4, c4 = (idx & 15) * 4;
        float f0 = t[c4 + 0][rn], f1 = t[c4 + 1][rn];
        float f2 = t[c4 + 2][rn], f3 = t[c4 + 3][rn];
        if (addI) {
            const int n = n0 + rn;
            if (k0 + c4 + 0 == n) f0 += 1.f;
            if (k0 + c4 + 1 == n) f1 += 1.f;
            if (k0 + c4 + 2 == n) f2 += 1.f;
            if (k0 + c4 + 3 == n) f3 += 1.f;
        }
        short4 p;
        p.x = f2bf(f0); p.y = f2bf(f1); p.z = f2bf(f2); p.w = f2bf(f3);
        *(short4*)(out + (size_t)(n0 + rn) * K + k0 + c4) = p;
    }
}

__device__ __forceinline__ void xcast_job(
    int j, const float* __restrict__ x, short* __restrict__ x_bf, int tid)
{
    const int i0 = j * 512 + tid;
    float4 v0 = reinterpret_cast<const float4*>(x)[i0];
    float4 v1 = reinterpret_cast<const float4*>(x)[i0 + 256];
    short4 p0, p1;
    p0.x = f2bf(v0.x); p0.y = f2bf(v0.y); p0.z = f2bf(v0.z); p0.w = f2bf(v0.w);
    p1.x = f2bf(v1.x); p1.y = f2bf(v1.y); p1.z = f2bf(v1.z); p1.w = f2bf(v1.w);
    reinterpret_cast<short4*>(x_bf)[i0] = p0;
    reinterpret_cast<short4*>(x_bf)[i0 + 256] = p1;
}

// ---------------------------------------------------------------------------
// ONE cooperative kernel, 512 blocks x 256 threads, phases split by grid.sync:
//  A: w1^T (256 jobs) | LayerNorm (128) | x-cast jobs 0..127 (128)
//  B: gemm2 ae@w1 full-K + bias+GELU fused (32 blocks)
//     || x-cast jobs 128..2047 + base^T+I (480 blocks)
//  C: gemm_w2: xw = h@w2 + b2, full-K, BM=128(all M) x BN=32 (512 blocks)
//  D: tpart: tp[ch][b][m][r] partial dots (1024 jobs, 2/block)
//  E: final: out = x@(base+I)^T' + t@x_b^T (512 blocks, 128x64 tiles)
// ---------------------------------------------------------------------------
__global__ __launch_bounds__(256, 2) void mega(
    const float* __restrict__ x, const float* __restrict__ ada,
    const float* __restrict__ base, const float* __restrict__ w1,
    const float* __restrict__ b1, const float* __restrict__ w2,
    const float* __restrict__ b2, const float* __restrict__ lng,
    const float* __restrict__ lnb, float* __restrict__ out,
    short* __restrict__ x_bf, short* __restrict__ w1t,
    short* __restrict__ baset, short* __restrict__ ae_bf,
    short* __restrict__ h_bf, float* __restrict__ xw,
    float* __restrict__ tp)
{
    __shared__ __align__(16) char smem[61440];   // 60 KB, reused per phase
    cg::grid_group grid = cg::this_grid();
    const int bid = blockIdx.x, tid = threadIdx.x;
    const int wave = tid >> 6, lane = tid & 63;
    const int quad = lane >> 4, r16 = lane & 15;
    float (*tT)[68] = (float(*)[68])smem;

    // ================= Phase A =================
    if (bid < 256) {
        tcast_tile(w1, w1t, NADA, NINT, bid & 15, bid >> 4, false, tid, tT);
    } else if (bid < 384) {
        const int b = bid - 256;
        const float* row = ada + (size_t)b * NADA;
        float sum = 0.f, sumsq = 0.f;
        for (int i = tid; i < NADA; i += 256) {
            float v = row[i];
            sum += v; sumsq += v * v;
        }
        #pragma unroll
        for (int off = 32; off > 0; off >>= 1) {
            sum   += __shfl_down(sum, off);
            sumsq += __shfl_down(sumsq, off);
        }
        float* s1 = &tT[0][0];
        float* s2 = &tT[1][0];
        const int wid = tid >> 6;
        if ((tid & 63) == 0) { s1[wid] = sum; s2[wid] = sumsq; }
        __syncthreads();
        if (tid == 0) {
            float a = 0.f, c = 0.f;
            for (int i = 0; i < 4; ++i) { a += s1[i]; c += s2[i]; }
            s1[0] = a; s2[0] = c;
        }
        __syncthreads();
        const float mu  = s1[0] * (1.f / NADA);
        const float var = s2[0] * (1.f / NADA) - mu * mu;
        const float inv = rsqrtf(var + LNEPS);
        for (int i = tid; i < NADA; i += 256) {
            ae_bf[(size_t)b * NADA + i] = f2bf((row[i] - mu) * inv * lng[i] + lnb[i]);
        }
    } else {
        xcast_job(bid - 384, x, x_bf, tid);
    }
    grid.sync();

    // ================= Phase B =================
    if (bid < 32) {
        // gemm2: 64x64 tile, full K=1024, BK=64 dbuf, fused bias+GELU
        short* As = (short*)smem;              // [2][2][64][32] = 16 KB
        short* Bs = (short*)(smem + 16384);    // 16 KB
        const int bn = (bid & 15) * 64, bm = (bid >> 4) * 64;
        const int wm0 = (wave >> 1) * 32, wn0 = (wave & 1) * 32;
        f32x4 acc[2][2] = {};
        auto stage = [&](int buf, int k0) {
            #pragma unroll
            for (int kk = 0; kk < 2; ++kk) {
                async16(ae_bf + (size_t)(bm + (tid >> 2)) * NADA + k0 + kk * 32 + (tid & 3) * 8,
                        &As[buf * 4096 + kk * 2048 + tid * 8]);
                async16(w1t + (size_t)(bn + (tid >> 2)) * NADA + k0 + kk * 32 + (tid & 3) * 8,
                        &Bs[buf * 4096 + kk * 2048 + tid * 8]);
            }
        };
        auto compute = [&](int buf) {
            #pragma unroll
            for (int kk = 0; kk < 2; ++kk) {
                bf16x8 af[2], bfr[2];
                #pragma unroll
                for (int i = 0; i < 2; ++i)
                    af[i] = *reinterpret_cast<const bf16x8*>(
                        &As[buf * 4096 + kk * 2048 + (wm0 + i * 16 + r16) * 32 + quad * 8]);
                #pragma unroll
                for (int j = 0; j < 2; ++j)
                    bfr[j] = *reinterpret_cast<const bf16x8*>(
                        &Bs[buf * 4096 + kk * 2048 + (wn0 + j * 16 + r16) * 32 + quad * 8]);
                #pragma unroll
                for (int i = 0; i < 2; ++i)
                    #pragma unroll
                    for (int j = 0; j < 2; ++j)
                        acc[i][j] = __builtin_amdgcn_mfma_f32_16x16x32_bf16(
                            af[i], bfr[j], acc[i][j], 0, 0, 0);
            }
        };
        stage(0, 0);
        __syncthreads();
        int cur = 0;
        for (int kt = 64; kt < NADA; kt += 64) {
            stage(cur ^ 1, kt);
            compute(cur);
            __syncthreads();
            cur ^= 1;
        }
        compute(cur);
        #pragma unroll
        for (int i = 0; i < 2; ++i) {
            #pragma unroll
            for (int r = 0; r < 4; ++r) {
                const int m = bm + wm0 + i * 16 + quad * 4 + r;
                #pragma unroll
                for (int j = 0; j < 2; ++j) {
                    const int n = bn + wn0 + j * 16 + r16;
                    float v = acc[i][j][r] + b1[n];
                    v = 0.5f * v * (1.f + erff(v * 0.70710678118654752f));
                    h_bf[(size_t)m * NINT + n] = f2bf(v);
                }
            }
        }
    } else {
        // 480 blocks: x-cast jobs 128..2047 (1920) + base^T+I tiles (256)
        for (int it = 0; it < 5; ++it) {
            const int jb = (bid - 32) + it * 480;
            if (jb < 1920) {
                xcast_job(128 + jb, x, x_bf, tid);
            } else if (jb < 2176) {
                const int bt = jb - 1920;
                tcast_tile(base, baset, DD, DD, bt & 15, bt >> 4, true, tid, tT);
            }
        }
    }
    grid.sync();

    // ================= Phase C: xw = h @ w2 + b2 (full-K) =================
    {
        // BM=128 (all M), BN=32; 512 blocks; BK=64 dbuf; w2 native fp32
        short* As = (short*)smem;              // [2][2][128][32] = 32 KB
        float* Bf = (float*)(smem + 32768);    // [2][2][32][32] = 16 KB
        const int bn = bid * 32;
        const int wm0 = wave * 32;
        f32x4 acc[2][2] = {};
        auto stage = [&](int buf, int k0) {
            #pragma unroll
            for (int kk = 0; kk < 2; ++kk) {
                #pragma unroll
                for (int s = 0; s < 2; ++s) {
                    const int c = s * 256 + tid;
                    async16(h_bf + (size_t)(c >> 2) * NINT + k0 + kk * 32 + (c & 3) * 8,
                            &As[buf * 8192 + kk * 4096 + c * 8]);
                }
                async16(w2 + (size_t)(k0 + kk * 32 + (tid >> 3)) * XWN + bn + (tid & 7) * 4,
                        &Bf[buf * 2048 + kk * 1024 + tid * 4]);
            }
        };
        auto compute = [&](int buf) {
            #pragma unroll
            for (int kk = 0; kk < 2; ++kk) {
                bf16x8 af[2], bfr[2];
                #pragma unroll
                for (int i = 0; i < 2; ++i)
                    af[i] = *reinterpret_cast<const bf16x8*>(
                        &As[buf * 8192 + kk * 4096 + (wm0 + i * 16 + r16) * 32 + quad * 8]);
                #pragma unroll
                for (int j = 0; j < 2; ++j) {
                    const int n = j * 16 + r16;
                    short tmp[8];
                    #pragma unroll
                    for (int t = 0; t < 8; ++t)
                        tmp[t] = f2bf(Bf[buf * 2048 + kk * 1024 + (quad * 8 + t) * 32 + n]);
                    bfr[j] = *reinterpret_cast<const bf16x8*>(tmp);
                }
                #pragma unroll
                for (int i = 0; i < 2; ++i)
                    #pragma unroll
                    for (int j = 0; j < 2; ++j)
                        acc[i][j] = __builtin_amdgcn_mfma_f32_16x16x32_bf16(
                            af[i], bfr[j], acc[i][j], 0, 0, 0);
            }
        };
        __syncthreads();   // LDS handoff from phase B usage
        stage(0, 0);
        __syncthreads();
        int cur = 0;
        for (int kt = 64; kt < NINT; kt += 64) {
            stage(cur ^ 1, kt);
            compute(cur);
            __syncthreads();
            cur ^= 1;
        }
        compute(cur);
        #pragma unroll
        for (int i = 0; i < 2; ++i) {
            #pragma unroll
            for (int r = 0; r < 4; ++r) {
                const int m = wm0 + i * 16 + quad * 4 + r;
                #pragma unroll
                for (int j = 0; j < 2; ++j) {
                    const int n = bn + j * 16 + r16;
                    xw[(size_t)m * XWN + n] = acc[i][j][r] + b2[n];
                }
            }
        }
    }
    grid.sync();

    // ================= Phase D: tpart =================
    {
        float* xa = (float*)smem;   // 4 KB chunk [c][r]
        #pragma unroll
        for (int it = 0; it < 2; ++it) {
            const int j = it * 512 + bid;
            const int b = j >> 3, ch = j & 7;
            const int col0 = ch * (DD / TKCH) * NRANK;  // x_a half: cols [0,8192)
            __syncthreads();   // protect xa reuse
            {
                const int i4 = tid * 4;
                *(float4*)(xa + i4) = *(const float4*)(xw + (size_t)b * XWN + col0 + i4);
            }
            __syncthreads();
            const int m = tid >> 3;
            const int r = tid & 7;
            const short* xrow = x_bf + ((size_t)b * TT + m) * DD + ch * (DD / TKCH);
            float accv = 0.f;
            #pragma unroll 2
            for (int c = 0; c < DD / TKCH; c += 8) {
                bf16x8 xr = *(const bf16x8*)(xrow + c);
                #pragma unroll
                for (int u = 0; u < 8; ++u)
                    accv += bf2f(xr[u]) * xa[(c + u) * NRANK + r];
            }
            tp[((size_t)ch * BB * TT + (size_t)b * TT + m) * NRANK + r] = accv;
        }
    }
    grid.sync();

    // ================= Phase E: final out = x@baset^T + t@x_b^T =================
    {
        // 128x64 tile, K=1024, BK=64 dbuf; LoRA epilogue
        short* As  = (short*)smem;              // [2][2][128][32] = 32 KB
        short* Bs  = (short*)(smem + 32768);    // [2][2][64][32]  = 16 KB
        float* tmS = (float*)(smem + 49152);    // [128][8] = 4 KB
        float* xbS = (float*)(smem + 53248);    // [4][64][8] = 8 KB
        const int bn = (bid & 15) * 64;
        const int bm = (bid >> 4) * 128;
        const int wm0 = (wave >> 1) * 64, wn0 = (wave & 1) * 32;

        __syncthreads();   // LDS handoff from phase D
        {
            // tmS = sum of TKCH chunks of tp for rows [bm, bm+128)
            float4 a = {0.f, 0.f, 0.f, 0.f};
            #pragma unroll
            for (int ch = 0; ch < TKCH; ++ch) {
                float4 v = *(const float4*)(tp + (size_t)ch * BB * TT * NRANK
                                               + (size_t)bm * 8 + tid * 4);
                a.x += v.x; a.y += v.y; a.z += v.z; a.w += v.w;
            }
            *(float4*)&tmS[tid * 4] = a;
            // xbS = x_b slice (xw already includes b2)
            const int b0 = bm >> 5;
            const int grp = tid >> 6;
            const int inner = tid & 63;
            const size_t off = (size_t)(b0 + grp) * XWN + DD * NRANK
                             + (size_t)bn * 8 + inner * 8;
            float4 r0 = *(const float4*)(xw + off);
            float4 r1 = *(const float4*)(xw + off + 4);
            *(float4*)&xbS[grp * 512 + inner * 8]     = r0;
            *(float4*)&xbS[grp * 512 + inner * 8 + 4] = r1;
        }

        f32x4 acc[4][2] = {};
        auto stage = [&](int buf, int k0) {
            #pragma unroll
            for (int kk = 0; kk < 2; ++kk) {
                #pragma unroll
                for (int s = 0; s < 2; ++s) {
                    const int c = s * 256 + tid;
                    async16(x_bf + (size_t)(bm + (c >> 2)) * DD + k0 + kk * 32 + (c & 3) * 8,
                            &As[buf * 8192 + kk * 4096 + c * 8]);
                }
                async16(baset + (size_t)(bn + (tid >> 2)) * DD + k0 + kk * 32 + (tid & 3) * 8,
                        &Bs[buf * 4096 + kk * 2048 + tid * 8]);
            }
        };
        auto compute = [&](int buf) {
            #pragma unroll
            for (int kk = 0; kk < 2; ++kk) {
                bf16x8 af[4], bfr[2];
                #pragma unroll
                for (int i = 0; i < 4; ++i)
                    af[i] = *reinterpret_cast<const bf16x8*>(
                        &As[buf * 8192 + kk * 4096 + (wm0 + i * 16 + r16) * 32 + quad * 8]);
                #pragma unroll
                for (int j = 0; j < 2; ++j)
                    bfr[j] = *reinterpret_cast<const bf16x8*>(
                        &Bs[buf * 4096 + kk * 2048 + (wn0 + j * 16 + r16) * 32 + quad * 8]);
                #pragma unroll
                for (int i = 0; i < 4; ++i)
                    #pragma unroll
                    for (int j = 0; j < 2; ++j)
                        acc[i][j] = __builtin_amdgcn_mfma_f32_16x16x32_bf16(
                            af[i], bfr[j], acc[i][j], 0, 0, 0);
            }
        };
        stage(0, 0);
        __syncthreads();
        int cur = 0;
        for (int kt = 64; kt < DD; kt += 64) {
            stage(cur ^ 1, kt);
            compute(cur);
            __syncthreads();
            cur ^= 1;
        }
        compute(cur);

        // epilogue: out = acc + tm @ xb^T
        float xbr[2][8];
        #pragma unroll
        for (int i = 0; i < 4; ++i) {
            const int mlBase = wm0 + i * 16 + quad * 4;
            const int s = mlBase >> 5;
            #pragma unroll
            for (int j = 0; j < 2; ++j) {
                const int nl = wn0 + j * 16 + r16;
                #pragma unroll
                for (int rr = 0; rr < 8; ++rr)
                    xbr[j][rr] = xbS[(s * 64 + nl) * 8 + rr];
            }
            #pragma unroll
            for (int r = 0; r < 4; ++r) {
                const int ml = mlBase + r;
                const int m = bm + ml;
                float t8[8];
                #pragma unroll
                for (int rr = 0; rr < 8; ++rr) t8[rr] = tmS[ml * 8 + rr];
                #pragma unroll
                for (int j = 0; j < 2; ++j) {
                    const int n = bn + wn0 + j * 16 + r16;
                    float v = acc[i][j][r];
                    #pragma unroll
                    for (int rr = 0; rr < 8; ++rr) v += t8[rr] * xbr[j][rr];
                    out[(size_t)m * DD + n] = v;
                }
            }
        }
    }
}

// ---------------------------------------------------------------------------
extern "C" void kernel_launch(void* const* d_in, const int* in_sizes, int n_in,
                              void* d_out, int out_size, void* d_ws, size_t ws_size,
                              hipStream_t stream)
{
    const float* x    = (const float*)d_in[0];
    const float* ada  = (const float*)d_in[1];
    const float* base = (const float*)d_in[2];
    const float* w1   = (const float*)d_in[3];
    const float* b1   = (const float*)d_in[4];
    const float* w2   = (const float*)d_in[5];
    const float* b2   = (const float*)d_in[6];
    const float* lng  = (const float*)d_in[7];
    const float* lnb  = (const float*)d_in[8];
    float* out = (float*)d_out;

    char* w = (char*)d_ws;
    short* x_bf  = (short*)w;  w += (size_t)8 << 20;   // 4096x1024 bf16
    short* w1t   = (short*)w;  w += (size_t)2 << 20;   // 1024x1024 bf16
    short* baset = (short*)w;  w += (size_t)2 << 20;   // 1024x1024 bf16 (base^T + I)
    short* ae_bf = (short*)w;  w += (size_t)256 << 10; // 128x1024 bf16
    short* h_bf  = (short*)w;  w += (size_t)256 << 10; // 128x1024 bf16
    float* xw    = (float*)w;  w += (size_t)8 << 20;   // 128x16384 fp32 (h@w2+b2)
    float* tp    = (float*)w;                          // 8x128x32x8 fp32 (1 MB)

    void* args[] = {
        (void*)&x, (void*)&ada, (void*)&base, (void*)&w1, (void*)&b1,
        (void*)&w2, (void*)&b2, (void*)&lng, (void*)&lnb, (void*)&out,
        (void*)&x_bf, (void*)&w1t, (void*)&baset, (void*)&ae_bf,
        (void*)&h_bf, (void*)&xw, (void*)&tp
    };
    hipLaunchCooperativeKernel((void*)mega, dim3(512), dim3(256), args, 0, stream);
}

// Round 4
// 181.026 us; speedup vs baseline: 2.3427x; 2.3427x over previous
//
#include <hip/hip_runtime.h>
#include <hip/hip_bf16.h>
#include <math.h>

// Problem constants
#define BB    128
#define TT    32
#define DD    1024
#define NADA  1024
#define NINT  1024
#define NRANK 8
#define LNEPS 1e-5f
#define SPL2  8   // gemm2 k-splits
#define XWN   (2 * DD * NRANK)   // 16384

using bf16x8 = __attribute__((ext_vector_type(8))) short;
using f32x4  = __attribute__((ext_vector_type(4))) float;

__device__ __forceinline__ short f2bf(float f) {
    __hip_bfloat16 h = __float2bfloat16(f);  // RNE
    return *reinterpret_cast<short*>(&h);
}

__device__ __forceinline__ void async16(const void* g, void* l) {
    __builtin_amdgcn_global_load_lds(
        (const __attribute__((address_space(1))) void*)g,
        (__attribute__((address_space(3))) void*)l, 16, 0, 0);
}

// ---------------------------------------------------------------------------
// Mega prep kernel (one launch, all independent preprocessing):
//   [0, 2048)     : x cast -> bf16
//   [2048, 2304)  : w1 -> w1t bf16
//   [2304, 2560)  : base+I -> baset bf16
//   [2560, 2688)  : LayerNorm(ada) -> ae_bf
// ---------------------------------------------------------------------------
__device__ __forceinline__ void tcast_tile(
    const float* __restrict__ in, short* __restrict__ out, int K, int N,
    int bx, int by, bool addI, int tid, float (*t)[68])
{
    const int n0 = bx * 64, k0 = by * 64;
    #pragma unroll
    for (int it = 0; it < 4; ++it) {
        const int idx = it * 256 + tid;
        const int r = idx >> 4, c4 = (idx & 15) * 4;
        float4 v = *(const float4*)(in + (size_t)(k0 + r) * N + n0 + c4);
        t[r][c4 + 0] = v.x; t[r][c4 + 1] = v.y;
        t[r][c4 + 2] = v.z; t[r][c4 + 3] = v.w;
    }
    __syncthreads();
    #pragma unroll
    for (int it = 0; it < 4; ++it) {
        const int idx = it * 256 + tid;
        const int rn = idx >> 4, c4 = (idx & 15) * 4;
        float f0 = t[c4 + 0][rn], f1 = t[c4 + 1][rn];
        float f2 = t[c4 + 2][rn], f3 = t[c4 + 3][rn];
        if (addI) {
            const int n = n0 + rn;
            if (k0 + c4 + 0 == n) f0 += 1.f;
            if (k0 + c4 + 1 == n) f1 += 1.f;
            if (k0 + c4 + 2 == n) f2 += 1.f;
            if (k0 + c4 + 3 == n) f3 += 1.f;
        }
        short4 p;
        p.x = f2bf(f0); p.y = f2bf(f1); p.z = f2bf(f2); p.w = f2bf(f3);
        *(short4*)(out + (size_t)(n0 + rn) * K + k0 + c4) = p;
    }
}

__global__ __launch_bounds__(256) void prep_kernel(
    const float* __restrict__ x, const float* __restrict__ w1,
    const float* __restrict__ base, const float* __restrict__ ada,
    const float* __restrict__ lng, const float* __restrict__ lnb,
    short* __restrict__ x_bf, short* __restrict__ w1t,
    short* __restrict__ baset, short* __restrict__ ae_bf)
{
    __shared__ float t[64][68];
    const int bid = blockIdx.x, tid = threadIdx.x;

    if (bid < 2048) {
        const int i0 = bid * 512 + tid;
        float4 v0 = reinterpret_cast<const float4*>(x)[i0];
        float4 v1 = reinterpret_cast<const float4*>(x)[i0 + 256];
        short4 p0, p1;
        p0.x = f2bf(v0.x); p0.y = f2bf(v0.y); p0.z = f2bf(v0.z); p0.w = f2bf(v0.w);
        p1.x = f2bf(v1.x); p1.y = f2bf(v1.y); p1.z = f2bf(v1.z); p1.w = f2bf(v1.w);
        reinterpret_cast<short4*>(x_bf)[i0] = p0;
        reinterpret_cast<short4*>(x_bf)[i0 + 256] = p1;
    } else if (bid < 2304) {
        const int b = bid - 2048;
        tcast_tile(w1, w1t, NADA, NINT, b & 15, b >> 4, false, tid, t);
    } else if (bid < 2560) {
        const int b = bid - 2304;
        tcast_tile(base, baset, DD, DD, b & 15, b >> 4, true, tid, t);
    } else {
        // LayerNorm, one block per sample
        const int b = bid - 2560;
        const float* row = ada + (size_t)b * NADA;
        float sum = 0.f, sumsq = 0.f;
        for (int i = tid; i < NADA; i += 256) {
            float v = row[i];
            sum += v; sumsq += v * v;
        }
        #pragma unroll
        for (int off = 32; off > 0; off >>= 1) {
            sum   += __shfl_down(sum, off);
            sumsq += __shfl_down(sumsq, off);
        }
        float* s1 = &t[0][0];
        float* s2 = &t[1][0];
        const int wid = tid >> 6, lane = tid & 63;
        if (lane == 0) { s1[wid] = sum; s2[wid] = sumsq; }
        __syncthreads();
        if (tid == 0) {
            float a = 0.f, c = 0.f;
            for (int i = 0; i < 4; ++i) { a += s1[i]; c += s2[i]; }
            s1[0] = a; s2[0] = c;
        }
        __syncthreads();
        const float mu  = s1[0] * (1.f / NADA);
        const float var = s2[0] * (1.f / NADA) - mu * mu;
        const float inv = rsqrtf(var + LNEPS);
        for (int i = tid; i < NADA; i += 256) {
            ae_bf[(size_t)b * NADA + i] = f2bf((row[i] - mu) * inv * lng[i] + lnb[i]);
        }
    }
}

// ---------------------------------------------------------------------------
// gemm2: split-K partials to C[z][M][N]. A (M,K), Bt (N,K) bf16 row-major.
// BK=64 single-buffer (round-1 structure, best measured).
// ---------------------------------------------------------------------------
__global__ __launch_bounds__(256, 2) void mgemm2(
    const short* __restrict__ A, const short* __restrict__ Bt,
    float* __restrict__ C, int kLen)
{
    constexpr int BM = 64, BN = 64;
    __shared__ __align__(16) short As[BM * 64];   // [2kk][64][32]
    __shared__ __align__(16) short Bs[BN * 64];

    const int bm = blockIdx.y * BM;
    const int bn = blockIdx.x * BN;
    const int kStart = blockIdx.z * kLen;
    const int tid = threadIdx.x;
    const int wave = tid >> 6, lane = tid & 63;
    const int wm0 = (wave >> 1) * 32;
    const int wn0 = (wave & 1) * 32;
    const int quad = lane >> 4, r16 = lane & 15;

    f32x4 acc[2][2] = {};

    for (int kt = 0; kt < kLen; kt += 64) {
        const int k0 = kStart + kt;
        #pragma unroll
        for (int kk = 0; kk < 2; ++kk) {
            async16(A + (size_t)(bm + (tid >> 2)) * NADA + k0 + kk * 32 + (tid & 3) * 8,
                    &As[kk * 2048 + tid * 8]);
            async16(Bt + (size_t)(bn + (tid >> 2)) * NADA + k0 + kk * 32 + (tid & 3) * 8,
                    &Bs[kk * 2048 + tid * 8]);
        }
        __syncthreads();
        #pragma unroll
        for (int kk = 0; kk < 2; ++kk) {
            bf16x8 af[2], bfr[2];
            #pragma unroll
            for (int i = 0; i < 2; ++i)
                af[i] = *reinterpret_cast<const bf16x8*>(
                    &As[kk * 2048 + (wm0 + i * 16 + r16) * 32 + quad * 8]);
            #pragma unroll
            for (int j = 0; j < 2; ++j)
                bfr[j] = *reinterpret_cast<const bf16x8*>(
                    &Bs[kk * 2048 + (wn0 + j * 16 + r16) * 32 + quad * 8]);
            #pragma unroll
            for (int i = 0; i < 2; ++i)
                #pragma unroll
                for (int j = 0; j < 2; ++j)
                    acc[i][j] = __builtin_amdgcn_mfma_f32_16x16x32_bf16(
                        af[i], bfr[j], acc[i][j], 0, 0, 0);
        }
        __syncthreads();
    }

    #pragma unroll
    for (int i = 0; i < 2; ++i) {
        #pragma unroll
        for (int r = 0; r < 4; ++r) {
            const int m = bm + wm0 + i * 16 + quad * 4 + r;
            #pragma unroll
            for (int j = 0; j < 2; ++j) {
                const int n = bn + wn0 + j * 16 + r16;
                C[((size_t)blockIdx.z * BB + m) * NINT + n] = acc[i][j][r];
            }
        }
    }
}

// ---------------------------------------------------------------------------
// Combine gemm2 split-K partials + bias + exact GELU -> h (bf16), float4-wide
// ---------------------------------------------------------------------------
__global__ __launch_bounds__(256) void combine_gelu(
    const float* __restrict__ part, const float* __restrict__ b1,
    short* __restrict__ h)
{
    const int i4 = (blockIdx.x * 256 + threadIdx.x) * 4;  // < 128*1024
    float4 s = *(const float4*)(b1 + (i4 & (NINT - 1)));
    #pragma unroll
    for (int z = 0; z < SPL2; ++z) {
        float4 p = *(const float4*)(part + (size_t)z * BB * NINT + i4);
        s.x += p.x; s.y += p.y; s.z += p.z; s.w += p.w;
    }
    s.x = 0.5f * s.x * (1.f + erff(s.x * 0.70710678118654752f));
    s.y = 0.5f * s.y * (1.f + erff(s.y * 0.70710678118654752f));
    s.z = 0.5f * s.z * (1.f + erff(s.z * 0.70710678118654752f));
    s.w = 0.5f * s.w * (1.f + erff(s.w * 0.70710678118654752f));
    short4 o;
    o.x = f2bf(s.x); o.y = f2bf(s.y); o.z = f2bf(s.z); o.w = f2bf(s.w);
    *(short4*)(h + i4) = o;
}

// ---------------------------------------------------------------------------
// gemm_w2 FULL-K (256 blocks): xw = h_bf @ w2 + b2. w2 read NATIVE (K,N)
// fp32; transpose+cast read-side in LDS. Epilogue writes FINAL products:
//   n < 8192  : x_a transposed+cast -> xat[m][r][c] bf16 (2 MB)
//   n >= 8192 : x_b (+b2) fp32 -> xwb[m][n-8192] (4 MB)
// No partials, no downstream summing.
// ---------------------------------------------------------------------------
__global__ __launch_bounds__(256, 2) void gemm_w2(
    const short* __restrict__ A, const float* __restrict__ W,
    const float* __restrict__ b2,
    short* __restrict__ xat, float* __restrict__ xwb)
{
    constexpr int BN = 64;
    __shared__ __align__(16) short As[128 * 64];   // 16 KB [2kk][128][32]
    __shared__ __align__(16) float Bf[64 * BN];    // 16 KB [2kk][32][64] native

    const int bn = blockIdx.x * BN;
    const int tid = threadIdx.x;
    const int wave = tid >> 6, lane = tid & 63;
    const int wm0 = (wave >> 1) * 64;
    const int wn0 = (wave & 1) * 32;
    const int quad = lane >> 4, r16 = lane & 15;

    f32x4 acc[4][2] = {};

    for (int kt = 0; kt < NINT; kt += 64) {
        #pragma unroll
        for (int kk = 0; kk < 2; ++kk) {
            #pragma unroll
            for (int s = 0; s < 2; ++s) {   // A: 128x32 bf16 per chunk
                const int c = s * 256 + tid;
                async16(A + (size_t)(c >> 2) * NINT + kt + kk * 32 + (c & 3) * 8,
                        &As[kk * 4096 + c * 8]);
            }
            #pragma unroll
            for (int s = 0; s < 2; ++s) {   // B: 32x64 fp32 per chunk, native
                const int c = s * 256 + tid;
                async16(W + (size_t)(kt + kk * 32 + (c >> 4)) * XWN + bn + (c & 15) * 4,
                        &Bf[kk * 2048 + c * 4]);
            }
        }
        __syncthreads();
        #pragma unroll
        for (int kk = 0; kk < 2; ++kk) {
            bf16x8 af[4], bfr[2];
            #pragma unroll
            for (int i = 0; i < 4; ++i)
                af[i] = *reinterpret_cast<const bf16x8*>(
                    &As[kk * 4096 + (wm0 + i * 16 + r16) * 32 + quad * 8]);
            #pragma unroll
            for (int j = 0; j < 2; ++j) {
                const int n = wn0 + j * 16 + r16;
                short tmp[8];
                #pragma unroll
                for (int t = 0; t < 8; ++t)
                    tmp[t] = f2bf(Bf[kk * 2048 + (quad * 8 + t) * BN + n]);
                bfr[j] = *reinterpret_cast<const bf16x8*>(tmp);
            }
            #pragma unroll
            for (int i = 0; i < 4; ++i)
                #pragma unroll
                for (int j = 0; j < 2; ++j)
                    acc[i][j] = __builtin_amdgcn_mfma_f32_16x16x32_bf16(
                        af[i], bfr[j], acc[i][j], 0, 0, 0);
        }
        __syncthreads();
    }

    const bool isA = (bn < DD * NRANK);   // uniform per block
    #pragma unroll
    for (int i = 0; i < 4; ++i) {
        #pragma unroll
        for (int r = 0; r < 4; ++r) {
            const int m = wm0 + i * 16 + quad * 4 + r;
            #pragma unroll
            for (int j = 0; j < 2; ++j) {
                const int n = bn + wn0 + j * 16 + r16;
                const float v = acc[i][j][r] + b2[n];
                if (isA)
                    xat[(size_t)m * (NRANK * DD) + (n & 7) * DD + (n >> 3)] = f2bf(v);
                else
                    xwb[(size_t)m * (NRANK * DD) + (n - DD * NRANK)] = v;
            }
        }
    }
}

// ---------------------------------------------------------------------------
// Final GEMM + fused rank-8 per-sample t = x @ x_a (tpart kernel deleted):
//   out[m][n] = sum_k x[m,k]*(base^T+I)[n,k]  +  sum_r t[m][r]*x_b[n][r]
// t computed in the same K-loop by 4 extra MFMAs reusing af[i]; B-fragment
// from xat (x_a^T bf16) staged 4 KB/iter with one async16/thread.
// 512 blocks, BM=128 x BN=64, BK=64 single-buffer.
// ---------------------------------------------------------------------------
__global__ __launch_bounds__(256, 2) void fgemm(
    const short* __restrict__ A,     // x_bf   [4096][1024]
    const short* __restrict__ Bt,    // baset  [1024][1024] = base^T + I
    const short* __restrict__ xat,   // [128][8][1024] bf16
    const float* __restrict__ xwb,   // [128][8192] fp32 (x_b + b2)
    float* __restrict__ C)           // out [4096][1024]
{
    __shared__ __align__(16) short As[128 * 64];   // 16 KB [2kk][128][32]
    __shared__ __align__(16) short Bs[64 * 64];    //  8 KB [2kk][64][32]
    __shared__ __align__(16) short xaS[32 * 64];   //  4 KB [4s*8r][64c]
    __shared__ float tmS[128 * 8];                 //  4 KB
    __shared__ float xbS[4 * 64 * 8];              //  8 KB

    const int bn = blockIdx.x * 64;
    const int bm = blockIdx.y * 128;
    const int b0 = bm >> 5;                 // first sample of this block
    const int tid = threadIdx.x;
    const int wave = tid >> 6, lane = tid & 63;
    const int wm0 = (wave >> 1) * 64;
    const int wn0 = (wave & 1) * 32;
    const int quad = lane >> 4, r16 = lane & 15;
    const int w2s = (wave >> 1) * 2;        // first sample of this wave's rows

    // prologue: stage x_b slice (already includes b2)
    {
        const int grp = tid >> 6, inner = tid & 63;
        const size_t off = (size_t)(b0 + grp) * (NRANK * DD) + (size_t)bn * 8 + inner * 8;
        float4 r0 = *(const float4*)(xwb + off);
        float4 r1 = *(const float4*)(xwb + off + 4);
        *(float4*)&xbS[grp * 512 + inner * 8]     = r0;
        *(float4*)&xbS[grp * 512 + inner * 8 + 4] = r1;
    }

    f32x4 acc[4][2] = {};
    f32x4 at[4] = {};

    for (int kt = 0; kt < DD; kt += 64) {
        #pragma unroll
        for (int kk = 0; kk < 2; ++kk) {
            #pragma unroll
            for (int s = 0; s < 2; ++s) {
                const int c = s * 256 + tid;
                async16(A + (size_t)(bm + (c >> 2)) * DD + kt + kk * 32 + (c & 3) * 8,
                        &As[kk * 4096 + c * 8]);
            }
            async16(Bt + (size_t)(bn + (tid >> 2)) * DD + kt + kk * 32 + (tid & 3) * 8,
                    &Bs[kk * 2048 + tid * 8]);
        }
        // x_a^T: 32 rows (4 samples x 8 ranks) x 64 k, covers both kk chunks
        async16(xat + ((size_t)(b0 + (tid >> 6)) * 8 + ((tid >> 3) & 7)) * DD
                    + kt + (tid & 7) * 8,
                &xaS[(tid >> 3) * 64 + (tid & 7) * 8]);
        __syncthreads();
        #pragma unroll
        for (int kk = 0; kk < 2; ++kk) {
            bf16x8 af[4], bfr[2], bft[2];
            #pragma unroll
            for (int i = 0; i < 4; ++i)
                af[i] = *reinterpret_cast<const bf16x8*>(
                    &As[kk * 4096 + (wm0 + i * 16 + r16) * 32 + quad * 8]);
            #pragma unroll
            for (int j = 0; j < 2; ++j)
                bfr[j] = *reinterpret_cast<const bf16x8*>(
                    &Bs[kk * 2048 + (wn0 + j * 16 + r16) * 32 + quad * 8]);
            #pragma unroll
            for (int u = 0; u < 2; ++u)
                bft[u] = *reinterpret_cast<const bf16x8*>(
                    &xaS[((w2s + u) * 8 + (r16 & 7)) * 64 + kk * 32 + quad * 8]);
            #pragma unroll
            for (int i = 0; i < 4; ++i) {
                #pragma unroll
                for (int j = 0; j < 2; ++j)
                    acc[i][j] = __builtin_amdgcn_mfma_f32_16x16x32_bf16(
                        af[i], bfr[j], acc[i][j], 0, 0, 0);
                at[i] = __builtin_amdgcn_mfma_f32_16x16x32_bf16(
                    af[i], bft[i >> 1], at[i], 0, 0, 0);
            }
        }
        __syncthreads();
    }

    // t -> LDS (D layout: col = lane&15 = rank, row = quad*4 + reg).
    // Waves 0/1 (and 2/3) write identical rows - benign duplicate.
    if (r16 < 8) {
        #pragma unroll
        for (int i = 0; i < 4; ++i)
            #pragma unroll
            for (int r = 0; r < 4; ++r)
                tmS[(wm0 + i * 16 + quad * 4 + r) * 8 + r16] = at[i][r];
    }
    __syncthreads();

    // epilogue: out = acc + t @ x_b^T
    float xbr[2][8];
    #pragma unroll
    for (int i = 0; i < 4; ++i) {
        const int mlBase = wm0 + i * 16 + quad * 4;
        const int s = mlBase >> 5;
        #pragma unroll
        for (int j = 0; j < 2; ++j) {
            const int nl = wn0 + j * 16 + r16;
            #pragma unroll
            for (int rr = 0; rr < 8; ++rr)
                xbr[j][rr] = xbS[(s * 64 + nl) * 8 + rr];
        }
        #pragma unroll
        for (int r = 0; r < 4; ++r) {
            const int ml = mlBase + r;
            const int m = bm + ml;
            float t8[8];
            #pragma unroll
            for (int rr = 0; rr < 8; ++rr) t8[rr] = tmS[ml * 8 + rr];
            #pragma unroll
            for (int j = 0; j < 2; ++j) {
                const int n = bn + wn0 + j * 16 + r16;
                float v = acc[i][j][r];
                #pragma unroll
                for (int rr = 0; rr < 8; ++rr) v += t8[rr] * xbr[j][rr];
                C[(size_t)m * DD + n] = v;
            }
        }
    }
}

// ---------------------------------------------------------------------------
extern "C" void kernel_launch(void* const* d_in, const int* in_sizes, int n_in,
                              void* d_out, int out_size, void* d_ws, size_t ws_size,
                              hipStream_t stream)
{
    const float* x    = (const float*)d_in[0];
    const float* ada  = (const float*)d_in[1];
    const float* base = (const float*)d_in[2];
    const float* w1   = (const float*)d_in[3];
    const float* b1   = (const float*)d_in[4];
    const float* w2   = (const float*)d_in[5];
    const float* b2   = (const float*)d_in[6];
    const float* lng  = (const float*)d_in[7];
    const float* lnb  = (const float*)d_in[8];
    float* out = (float*)d_out;

    char* w = (char*)d_ws;
    short* x_bf  = (short*)w;  w += (size_t)8 << 20;   // 4096x1024 bf16
    short* w1t   = (short*)w;  w += (size_t)2 << 20;   // 1024x1024 bf16
    short* baset = (short*)w;  w += (size_t)2 << 20;   // 1024x1024 bf16 (base^T + I)
    short* ae_bf = (short*)w;  w += (size_t)256 << 10; // 128x1024 bf16
    short* h_bf  = (short*)w;  w += (size_t)256 << 10; // 128x1024 bf16
    short* xat   = (short*)w;  w += (size_t)2 << 20;   // 128x8x1024 bf16 (x_a^T)
    float* xwb   = (float*)w;  w += (size_t)4 << 20;   // 128x8192 fp32 (x_b + b2)
    float* part  = (float*)w;                          // 8x128x1024 fp32 (4 MB)

    // 1. all preprocessing in one launch (2688 blocks)
    prep_kernel<<<2688, 256, 0, stream>>>(
        x, w1, base, ada, lng, lnb, x_bf, w1t, baset, ae_bf);
    // 2. ae@w1 split-K partials (256 blocks), then gelu+bias -> h_bf
    mgemm2<<<dim3(NINT / 64, BB / 64, SPL2), 256, 0, stream>>>(
        ae_bf, w1t, part, NADA / SPL2);
    combine_gelu<<<BB * NINT / 1024, 256, 0, stream>>>(part, b1, h_bf);
    // 3. full-K h@w2 + b2 -> xat (bf16 x_a^T) + xwb (fp32 x_b), 256 blocks
    gemm_w2<<<XWN / 64, 256, 0, stream>>>(h_bf, w2, b2, xat, xwb);
    // 4. final: out = x@(base+I)^T + (x@x_a)@x_b^T, t fused in-loop (512 blocks)
    fgemm<<<dim3(DD / 64, BB * TT / 128), 256, 0, stream>>>(
        x_bf, baset, xat, xwb, out);
}